// Round 6
// baseline (234.362 us; speedup 1.0000x reference)
//
#include <hip/hip_runtime.h>

#define TAU 0.2f
#define VTH 0.3f

typedef float v4f __attribute__((ext_vector_type(4)));

#define BLOCKS 2048
#define THREADS 256
#define NPIX (32 * 128 * 32 * 32)          // 4194304
#define NTH (BLOCKS * THREADS)             // 524288
#define ITERS (NPIX / NTH)                 // 8 pixels per thread, exact

// R5 pattern with ONE variable changed: per-wave MLP depth 2 -> 16.
// All 16 dwordx4 loads (8 pixels) issue up front; compute for pixel k only
// depends on the 2 oldest outstanding loads, so the compiler emits partial
// s_waitcnt vmcnt(14/12/10/...) and the vmem queue stays deep for the whole
// kernel. No LDS, no barriers -> nothing ever drains the queue to 0.
// Stores stay NORMAL/cached (R4 proved nt on non-line-dense stores causes
// 3x HBM write amplification; L2 merges the dense-span pairs fine).
__global__ __launch_bounds__(256) void LIFSpike_73864847556979_kernel(
    const float* __restrict__ x, float* __restrict__ out) {
    const int tid = blockIdx.x * THREADS + threadIdx.x;

    const v4f* __restrict__ xin = (const v4f*)x;
    v4f* __restrict__ xout = (v4f*)out;

    v4f buf[ITERS][2];
    // Issue everything: 16 independent global_load_dwordx4 in flight.
#pragma unroll
    for (int it = 0; it < ITERS; ++it) {
        const size_t b = ((size_t)tid + (size_t)it * NTH) * 2;
        buf[it][0] = xin[b];
        buf[it][1] = xin[b + 1];
    }

    // Drain in issue order with partial vmcnt waits; stores fire-and-forget.
#pragma unroll
    for (int it = 0; it < ITERS; ++it) {
        const size_t b = ((size_t)tid + (size_t)it * NTH) * 2;
        v4f a = buf[it][0];
        v4f bb = buf[it][1];
        float v[8] = {a.x, a.y, a.z, a.w, bb.x, bb.y, bb.z, bb.w};
        float r[8];
        float u = 0.0f, o = 0.0f;
#pragma unroll
        for (int k = 0; k < 8; ++k) {
            u = TAU * u * (1.0f - o) + v[k];
            o = (u > VTH) ? 1.0f : 0.0f;
            r[k] = o;
        }
        xout[b] = (v4f){r[0], r[1], r[2], r[3]};
        xout[b + 1] = (v4f){r[4], r[5], r[6], r[7]};
    }
}

extern "C" void kernel_launch(void* const* d_in, const int* in_sizes, int n_in,
                              void* d_out, int out_size, void* d_ws, size_t ws_size,
                              hipStream_t stream) {
    const float* x = (const float*)d_in[0];
    float* out = (float*)d_out;
    // NPIX == BLOCKS*THREADS*ITERS exactly (4194304 = 2048*256*8).
    LIFSpike_73864847556979_kernel<<<BLOCKS, THREADS, 0, stream>>>(x, out);
}